// Round 8
// baseline (522.854 us; speedup 1.0000x reference)
//
#include <hip/hip_runtime.h>
#include <hip/hip_bf16.h>

// Qwen2 decoder-layer fragment (Q path only — K/V are dead downstream):
//   h = rmsnorm(x, ln_w); q = h@Wq^T + bq; q = rope(q, pos); out = q@Wo^T + x
// out fp32 [8192, 3584].

#define HIDDEN   3584
#define NQ       3584
#define NTOK     8192
#define NPAIR    64
#define EPSV     1e-6f

typedef __hip_bfloat16 bf16;
typedef __bf16 bf16x8 __attribute__((ext_vector_type(8)));
typedef float  f32x4  __attribute__((ext_vector_type(4)));
typedef float  f32x16 __attribute__((ext_vector_type(16)));

static __device__ __forceinline__ unsigned short f2bu(float f) {
  bf16 h = __float2bfloat16(f);
  return __builtin_bit_cast(unsigned short, h);
}
static __device__ __forceinline__ void stv(float* p, float v) { *p = v; }
static __device__ __forceinline__ void stv(bf16* p, float v) { *p = __float2bfloat16(v); }

// ---------------- fp32 -> bf16 weight conversion ----------------
__global__ __launch_bounds__(256)
void cvt_f32_bf16(const float* __restrict__ s, bf16* __restrict__ d, int n4) {
  int i = blockIdx.x * 256 + threadIdx.x;
  if (i >= n4) return;
  float4 f = ((const float4*)s)[i];
  ushort4 o;
  o.x = f2bu(f.x); o.y = f2bu(f.y); o.z = f2bu(f.z); o.w = f2bu(f.w);
  ((ushort4*)d)[i] = o;
}

// ---------------- RMSNorm: x fp32 [row, 3584] -> h bf16 ----------------
__global__ __launch_bounds__(256)
void rmsnorm_k(const float* __restrict__ x, const float* __restrict__ w,
               bf16* __restrict__ h) {
  const int row = blockIdx.x;
  const int t = threadIdx.x;
  const float4* xr = (const float4*)(x + (size_t)row * HIDDEN);
  const float4* wr = (const float4*)w;

  float4 v0 = xr[t], v1 = xr[t + 256], v2 = xr[t + 512];
  float4 v3 = make_float4(0.f, 0.f, 0.f, 0.f);
  if (t < 128) v3 = xr[t + 768];

  float ss = v0.x*v0.x + v0.y*v0.y + v0.z*v0.z + v0.w*v0.w
           + v1.x*v1.x + v1.y*v1.y + v1.z*v1.z + v1.w*v1.w
           + v2.x*v2.x + v2.y*v2.y + v2.z*v2.z + v2.w*v2.w
           + v3.x*v3.x + v3.y*v3.y + v3.z*v3.z + v3.w*v3.w;

#pragma unroll
  for (int off = 32; off > 0; off >>= 1) ss += __shfl_down(ss, off);
  __shared__ float red[4];
  if ((t & 63) == 0) red[t >> 6] = ss;
  __syncthreads();
  float tot = red[0] + red[1] + red[2] + red[3];
  float scale = rsqrtf(tot * (1.0f / HIDDEN) + EPSV);

  ushort4* hr = (ushort4*)(h + (size_t)row * HIDDEN);
  float4 w0 = wr[t], w1 = wr[t + 256], w2 = wr[t + 512];
  ushort4 o;
  o.x = f2bu(v0.x*scale*w0.x); o.y = f2bu(v0.y*scale*w0.y);
  o.z = f2bu(v0.z*scale*w0.z); o.w = f2bu(v0.w*scale*w0.w);
  hr[t] = o;
  o.x = f2bu(v1.x*scale*w1.x); o.y = f2bu(v1.y*scale*w1.y);
  o.z = f2bu(v1.z*scale*w1.z); o.w = f2bu(v1.w*scale*w1.w);
  hr[t + 256] = o;
  o.x = f2bu(v2.x*scale*w2.x); o.y = f2bu(v2.y*scale*w2.y);
  o.z = f2bu(v2.z*scale*w2.z); o.w = f2bu(v2.w*scale*w2.w);
  hr[t + 512] = o;
  if (t < 128) {
    float4 w3 = wr[t + 768];
    o.x = f2bu(v3.x*scale*w3.x); o.y = f2bu(v3.y*scale*w3.y);
    o.z = f2bu(v3.z*scale*w3.z); o.w = f2bu(v3.w*scale*w3.w);
    hr[t + 768] = o;
  }
}

// ---------------- per-token rope table ----------------
__global__ __launch_bounds__(256)
void rope_tab_k(const int* __restrict__ pos, float2* __restrict__ tab) {
  int idx = blockIdx.x * 256 + threadIdx.x;   // NTOK*64
  int t = idx >> 6;
  int i = idx & 63;
  float inv = exp2f(-(float)i * (19.931568569324174f / 64.0f));
  float ang = (float)pos[t] * inv;
  float s, c;
  sincosf(ang, &s, &c);
  tab[idx] = make_float2(c, s);
}

// ---------------- in-place neox rope on q bf16 [NTOK, 28, 128] ----------------
__global__ __launch_bounds__(256)
void rope_apply_k(bf16* __restrict__ q, const float2* __restrict__ tab) {
  const int t = blockIdx.x;
  bf16* qt = q + (size_t)t * NQ;
  const float2* tb = tab + (size_t)t * NPAIR;
  for (int j = threadIdx.x; j < 28 * NPAIR; j += 256) {
    int head = j >> 6;
    int i = j & 63;
    float2 cs = tb[i];
    int base = head * 128 + i;
    float x1 = __bfloat162float(qt[base]);
    float x2 = __bfloat162float(qt[base + 64]);
    qt[base]      = __float2bfloat16(x1 * cs.x - x2 * cs.y);
    qt[base + 64] = __float2bfloat16(x2 * cs.x + x1 * cs.y);
  }
}

// ================= 256x256 8-phase bf16 GEMM (C = A * B^T) ==================
// 8 waves (2M x 4N), BK=64 K-tiles, double-buffered LDS (128 KiB).
// R8: switch MFMA shape 16x16x32 -> 32x32x16 (2495 TF ceiling vs 2176; half
// the issue slots: 8 MFMA/phase). Identical LDS traffic (A 4 reads/phase,
// B 8 at q0), identical stagger + vmcnt ledger + swizzle as R7.
// Fragment maps (m74/m101-verified C/D; inputs mirror verified 16x16 analog):
//   A/B in: row(col) = lane&31, k = 8*(lane>>5) + j, j=0..7  (1 ds_read_b128)
//   C/D:    col = lane&31, row = (reg&3) + 8*(reg>>2) + 4*(lane>>5)
// Swizzle: LDS[row][slot^(row&7)] holds global[row][slot] (involution;
// conflict-free: any 8 consecutive lanes cover 8 distinct slots).
// Stage stagger (tile T_t -> buf t&1; B dead after its q0, AH0 after q1,
// AH1 after q3): ph0:T1.AH1 ph1:T2.Blo ph2:T2.Bhi ph3:T2.AH0 ph4:T2.AH1
//                ph5:T3.Blo ph6:T3.Bhi ph7:T3.AH0
// vmcnt ledger (2 instr/stage): end-ph3 VMW(6); end-ph7 VMW(6);
// last iter: end-ph3 VMW(2), end-ph5 VMW(0).
#define BMT 256
#define BNT 256
#define BKT 64

#define BARRIER() asm volatile("s_barrier" ::: "memory")
#define VMW(n)    asm volatile("s_waitcnt vmcnt(" #n ")" ::: "memory")

template <int MODE, typename OutT>   // MODE 0: +bias[col] -> OutT; MODE 1: +resid[row,col]
__global__ __launch_bounds__(512, 2)
void gemm256(const bf16* __restrict__ A, const bf16* __restrict__ B,
             const float* __restrict__ aux, OutT* __restrict__ C,
             int M, int N, int K) {
  __shared__ __align__(16) bf16 sA[2][BMT][BKT];   // 64 KiB
  __shared__ __align__(16) bf16 sB[2][BNT][BKT];   // 64 KiB

  const int tid  = threadIdx.x;
  const int wave = tid >> 6;     // 0..7
  const int lane = tid & 63;
  const int wm   = wave >> 2;    // 0..1
  const int wn   = wave & 3;     // 0..3
  const int l31  = lane & 31;
  const int hi   = lane >> 5;    // 0..1
  const int sx   = lane & 7;     // read-side slot XOR = row & 7

  // bijective XCD swizzle, bn-fast within an XCD (A panel hot in XCD L2)
  const int nwg = gridDim.x;           // 448, % 8 == 0
  const int cpx = nwg >> 3;
  const int swz = (blockIdx.x & 7) * cpx + (blockIdx.x >> 3);
  const int gn  = N / BNT;
  const int bm  = (swz / gn) * BMT;
  const int bn  = (swz % gn) * BNT;

  const bf16* Ab = A + (size_t)bm * K;
  const bf16* Bb = B + (size_t)bn * K;

  const int NT = K / BKT;   // 56 (even)

  // staging: one 64-row chunk (8KB): wave w rows [rbase+w*8,+8);
  // lane: row = l>>3, slot = l&7; source pre-swizzled slot = (l&7)^(row&7)
  const int srw = lane >> 3;    // 0..7  (== row&7)
  const int ssl = lane & 7;

  auto stage64 = [&](const bf16* gpanel, int kt, bf16* ldst, int rbase) {
    const int r  = rbase + wave * 8 + srw;            // tile-local row
    const int sg = ssl ^ srw;                         // pre-swizzled source slot
    const bf16* src = gpanel + (size_t)r * K + (size_t)kt * BKT + sg * 8;
    __builtin_amdgcn_global_load_lds(
        (const __attribute__((address_space(1))) void*)src,
        (__attribute__((address_space(3))) void*)(ldst + (size_t)(wave * 8) * BKT),
        16, 0, 0);
  };
  // kinds: 0=A_H0{0,128}, 1=A_H1{64,192}, 2=B_lo{0,64}, 3=B_hi{128,192}
  auto stage16k = [&](int kind, int buf, int kt) {
    if (kt >= NT) return;
    if (kind == 0)      { stage64(Ab, kt, &sA[buf][0][0],   0);   stage64(Ab, kt, &sA[buf][128][0], 128); }
    else if (kind == 1) { stage64(Ab, kt, &sA[buf][64][0],  64);  stage64(Ab, kt, &sA[buf][192][0], 192); }
    else if (kind == 2) { stage64(Bb, kt, &sB[buf][0][0],   0);   stage64(Bb, kt, &sB[buf][64][0],  64); }
    else                { stage64(Bb, kt, &sB[buf][128][0], 128); stage64(Bb, kt, &sB[buf][192][0], 192); }
  };

  f32x16 acc[4][2];   // [m-frag(phase)][n-frag]
#pragma unroll
  for (int i = 0; i < 4; ++i)
#pragma unroll
    for (int j = 0; j < 2; ++j)
      acc[i][j] = (f32x16){0.f,0.f,0.f,0.f,0.f,0.f,0.f,0.f,
                           0.f,0.f,0.f,0.f,0.f,0.f,0.f,0.f};

  bf16x8 bfr[2][4];   // B frags [n-frag][kk], loaded at q0, live q0-q3
  bf16x8 afr[4];      // A frags [kk] for the current phase's m-frag

  auto loadA = [&](int buf, int qq) {
    const int R = wm * 128 + qq * 32 + l31;
#pragma unroll
    for (int kk = 0; kk < 4; ++kk) {
      const int sp = (2 * kk + hi) ^ sx;
      afr[kk] = *(const bf16x8*)&sA[buf][R][sp * 8];
    }
  };
  auto loadB = [&](int buf) {
#pragma unroll
    for (int nf = 0; nf < 2; ++nf) {
      const int R = wn * 64 + nf * 32 + l31;
#pragma unroll
      for (int kk = 0; kk < 4; ++kk) {
        const int sp = (2 * kk + hi) ^ sx;
        bfr[nf][kk] = *(const bf16x8*)&sB[buf][R][sp * 8];
      }
    }
  };
  auto domfma = [&](int q) {
#pragma unroll
    for (int nf = 0; nf < 2; ++nf)
#pragma unroll
      for (int kk = 0; kk < 4; ++kk)
        acc[q][nf] = __builtin_amdgcn_mfma_f32_32x32x16_bf16(
            afr[kk], bfr[nf][kk], acc[q][nf], 0, 0, 0);
  };

  // prologue: tile0 complete (8 instr/wave), tile1 B + A_H0 (6 instr/wave)
  stage16k(2, 0, 0); stage16k(3, 0, 0); stage16k(0, 0, 0); stage16k(1, 0, 0);
  stage16k(2, 1, 1); stage16k(3, 1, 1); stage16k(0, 1, 1);
  VMW(6);   // tile0 fully landed
  BARRIER();

  const int nit = NT / 2;   // 28

  for (int it = 0; it < nit; ++it) {
    const bool last = (it == nit - 1);
#pragma unroll
    for (int u = 0; u < 2; ++u) {          // tile kt = 2*it+u, buf u
#pragma unroll
      for (int q = 0; q < 4; ++q) {        // phase = one 32-row m-frag
        const int ph = u * 4 + q;
        // ---- ds_read this phase's fragments (compiler-managed waits) ----
        loadA(u, q);
        if (q == 0) loadB(u);
        // ---- staggered 16KB stage (targets proven-dead regions) ----
        if (ph == 0)      stage16k(1, 1, 2 * it + 1);   // A_H1 of tile 2it+1
        else if (ph == 1) stage16k(2, 0, 2 * it + 2);   // B_lo  tile 2it+2
        else if (ph == 2) stage16k(3, 0, 2 * it + 2);   // B_hi
        else if (ph == 3) stage16k(0, 0, 2 * it + 2);   // A_H0
        else if (ph == 4) stage16k(1, 0, 2 * it + 2);   // A_H1
        else if (ph == 5) stage16k(2, 1, 2 * it + 3);   // B_lo  tile 2it+3
        else if (ph == 6) stage16k(3, 1, 2 * it + 3);   // B_hi
        else              stage16k(0, 1, 2 * it + 3);   // A_H0
        BARRIER();
        __builtin_amdgcn_s_setprio(1);
        domfma(q);
        __builtin_amdgcn_s_setprio(0);
        // ---- counted vmcnt waits (ledger in header comment) ----
        if (ph == 3) {
          if (!last) { VMW(6); } else { VMW(2); }
        } else if (ph == 5) {
          if (last)  { VMW(0); }
        } else if (ph == 7) {
          if (!last) { VMW(6); }
        }
        BARRIER();
      }
    }
  }

  // epilogue: C/D 32x32: col = lane&31, row = (reg&3) + 8*(reg>>2) + 4*hi
#pragma unroll
  for (int mf = 0; mf < 4; ++mf) {
#pragma unroll
    for (int nf = 0; nf < 2; ++nf) {
      const int col = bn + wn * 64 + nf * 32 + l31;
#pragma unroll
      for (int r = 0; r < 16; ++r) {
        const int row = bm + wm * 128 + mf * 32 + (r & 3) + 8 * (r >> 2) + 4 * hi;
        float v = acc[mf][nf][r];
        if (MODE == 0) v += aux[col];
        else           v += aux[(size_t)row * N + col];
        stv(&C[(size_t)row * N + col], v);
      }
    }
  }
}

// ---------------- launch ----------------
extern "C" void kernel_launch(void* const* d_in, const int* in_sizes, int n_in,
                              void* d_out, int out_size, void* d_ws, size_t ws_size,
                              hipStream_t stream) {
  (void)in_sizes; (void)n_in; (void)out_size; (void)ws_size;
  const float* x    = (const float*)d_in[0];
  const int*   pos  = (const int*)d_in[1];
  const float* ln_w = (const float*)d_in[2];
  const float* Wq   = (const float*)d_in[3];
  const float* bq   = (const float*)d_in[4];
  const float* Wo   = (const float*)d_in[9];
  float* out = (float*)d_out;

  char* ws = (char*)d_ws;
  size_t off = 0;
  bf16* h    = (bf16*)(ws + off); off += (size_t)NTOK * HIDDEN * sizeof(bf16);
  bf16* q    = (bf16*)(ws + off); off += (size_t)NTOK * NQ * sizeof(bf16);
  bf16* Wqb  = (bf16*)(ws + off); off += (size_t)NQ * HIDDEN * sizeof(bf16);
  bf16* Wob  = (bf16*)(ws + off); off += (size_t)HIDDEN * NQ * sizeof(bf16);
  float2* tab = (float2*)(ws + off); off += (size_t)NTOK * NPAIR * sizeof(float2);

  const int n4 = NQ * HIDDEN / 4;
  cvt_f32_bf16<<<(n4 + 255) / 256, 256, 0, stream>>>(Wq, Wqb, n4);
  cvt_f32_bf16<<<(n4 + 255) / 256, 256, 0, stream>>>(Wo, Wob, n4);
  rmsnorm_k<<<NTOK, 256, 0, stream>>>(x, ln_w, h);
  rope_tab_k<<<(NTOK * NPAIR) / 256, 256, 0, stream>>>(pos, tab);

  const int nblk = (NTOK / BMT) * (NQ / BNT);   // 32 * 14 = 448 (%8 == 0)
  gemm256<0, bf16><<<nblk, 512, 0, stream>>>(h, Wqb, bq, q, NTOK, NQ, HIDDEN);
  rope_apply_k<<<NTOK, 256, 0, stream>>>(q, tab);
  gemm256<1, float><<<nblk, 512, 0, stream>>>(q, Wob, x, out, NTOK, HIDDEN, NQ);
}

// Round 9
// 496.231 us; speedup vs baseline: 1.0537x; 1.0537x over previous
//
#include <hip/hip_runtime.h>
#include <hip/hip_bf16.h>

// Qwen2 decoder-layer fragment (Q path only — K/V are dead downstream):
//   h = rmsnorm(x, ln_w); q = h@Wq^T + bq; q = rope(q, pos); out = q@Wo^T + x
// out fp32 [8192, 3584].

#define HIDDEN   3584
#define NQ       3584
#define NTOK     8192
#define NPAIR    64
#define EPSV     1e-6f

typedef __hip_bfloat16 bf16;
typedef __bf16 bf16x8 __attribute__((ext_vector_type(8)));
typedef float  f32x4  __attribute__((ext_vector_type(4)));

static __device__ __forceinline__ unsigned short f2bu(float f) {
  bf16 h = __float2bfloat16(f);
  return __builtin_bit_cast(unsigned short, h);
}
static __device__ __forceinline__ void stv(float* p, float v) { *p = v; }
static __device__ __forceinline__ void stv(bf16* p, float v) { *p = __float2bfloat16(v); }

// ---------------- fp32 -> bf16 weight conversion ----------------
__global__ __launch_bounds__(256)
void cvt_f32_bf16(const float* __restrict__ s, bf16* __restrict__ d, int n4) {
  int i = blockIdx.x * 256 + threadIdx.x;
  if (i >= n4) return;
  float4 f = ((const float4*)s)[i];
  ushort4 o;
  o.x = f2bu(f.x); o.y = f2bu(f.y); o.z = f2bu(f.z); o.w = f2bu(f.w);
  ((ushort4*)d)[i] = o;
}

// ---------------- RMSNorm: x fp32 [row, 3584] -> h bf16 ----------------
__global__ __launch_bounds__(256)
void rmsnorm_k(const float* __restrict__ x, const float* __restrict__ w,
               bf16* __restrict__ h) {
  const int row = blockIdx.x;
  const int t = threadIdx.x;
  const float4* xr = (const float4*)(x + (size_t)row * HIDDEN);
  const float4* wr = (const float4*)w;

  float4 v0 = xr[t], v1 = xr[t + 256], v2 = xr[t + 512];
  float4 v3 = make_float4(0.f, 0.f, 0.f, 0.f);
  if (t < 128) v3 = xr[t + 768];

  float ss = v0.x*v0.x + v0.y*v0.y + v0.z*v0.z + v0.w*v0.w
           + v1.x*v1.x + v1.y*v1.y + v1.z*v1.z + v1.w*v1.w
           + v2.x*v2.x + v2.y*v2.y + v2.z*v2.z + v2.w*v2.w
           + v3.x*v3.x + v3.y*v3.y + v3.z*v3.z + v3.w*v3.w;

#pragma unroll
  for (int off = 32; off > 0; off >>= 1) ss += __shfl_down(ss, off);
  __shared__ float red[4];
  if ((t & 63) == 0) red[t >> 6] = ss;
  __syncthreads();
  float tot = red[0] + red[1] + red[2] + red[3];
  float scale = rsqrtf(tot * (1.0f / HIDDEN) + EPSV);

  ushort4* hr = (ushort4*)(h + (size_t)row * HIDDEN);
  float4 w0 = wr[t], w1 = wr[t + 256], w2 = wr[t + 512];
  ushort4 o;
  o.x = f2bu(v0.x*scale*w0.x); o.y = f2bu(v0.y*scale*w0.y);
  o.z = f2bu(v0.z*scale*w0.z); o.w = f2bu(v0.w*scale*w0.w);
  hr[t] = o;
  o.x = f2bu(v1.x*scale*w1.x); o.y = f2bu(v1.y*scale*w1.y);
  o.z = f2bu(v1.z*scale*w1.z); o.w = f2bu(v1.w*scale*w1.w);
  hr[t + 256] = o;
  o.x = f2bu(v2.x*scale*w2.x); o.y = f2bu(v2.y*scale*w2.y);
  o.z = f2bu(v2.z*scale*w2.z); o.w = f2bu(v2.w*scale*w2.w);
  hr[t + 512] = o;
  if (t < 128) {
    float4 w3 = wr[t + 768];
    o.x = f2bu(v3.x*scale*w3.x); o.y = f2bu(v3.y*scale*w3.y);
    o.z = f2bu(v3.z*scale*w3.z); o.w = f2bu(v3.w*scale*w3.w);
    hr[t + 768] = o;
  }
}

// ---------------- per-token rope table ----------------
__global__ __launch_bounds__(256)
void rope_tab_k(const int* __restrict__ pos, float2* __restrict__ tab) {
  int idx = blockIdx.x * 256 + threadIdx.x;   // NTOK*64
  int t = idx >> 6;
  int i = idx & 63;
  float inv = exp2f(-(float)i * (19.931568569324174f / 64.0f));
  float ang = (float)pos[t] * inv;
  float s, c;
  sincosf(ang, &s, &c);
  tab[idx] = make_float2(c, s);
}

// ---------------- in-place neox rope on q bf16 [NTOK, 28, 128] ----------------
__global__ __launch_bounds__(256)
void rope_apply_k(bf16* __restrict__ q, const float2* __restrict__ tab) {
  const int t = blockIdx.x;
  bf16* qt = q + (size_t)t * NQ;
  const float2* tb = tab + (size_t)t * NPAIR;
  for (int j = threadIdx.x; j < 28 * NPAIR; j += 256) {
    int head = j >> 6;
    int i = j & 63;
    float2 cs = tb[i];
    int base = head * 128 + i;
    float x1 = __bfloat162float(qt[base]);
    float x2 = __bfloat162float(qt[base + 64]);
    qt[base]      = __float2bfloat16(x1 * cs.x - x2 * cs.y);
    qt[base + 64] = __float2bfloat16(x2 * cs.x + x1 * cs.y);
  }
}

// ================= 256x256 8-phase bf16 GEMM (C = A * B^T) ==================
// 8 waves (2M x 4N), BK=64 K-tiles, double-buffered LDS (128 KiB).
// R9: SOFT barriers — __builtin_amdgcn_s_barrier() carries no LLVM memory
// clobber (m201-exact), so ds_reads/staging may be compiler-scheduled across
// barriers; only the counted VMW() asm (volatile + memory clobber) orders
// memory. R5-R8 used asm s_barrier + "memory" = a full fence at every
// barrier (16/iter), forbidding the cross-phase overlap the schedule needs.
// Safety: vmcnt ledger never relied on the barrier as a compiler fence;
// gload_lds intrinsics can't cross VMW; hoisted ds_reads keep >=3-phase
// separation from their buffer's next staging write (checked per region).
// MFMA shape: 16x16x32 (R8's 32x32x16 regressed; reverted).
// Swizzle: slot' = slot ^ (row & 7) (involution; conflict-free, R5-verified:
// SQ_LDS_BANK_CONFLICT == 0). gload_lds dest linear, source pre-swizzled.
// Stage stagger (tile T_t -> buf t&1; B dead after its q0, AH0 after q1,
// AH1 after q3): ph0:T1.AH1 ph1:T2.Blo ph2:T2.Bhi ph3:T2.AH0 ph4:T2.AH1
//                ph5:T3.Blo ph6:T3.Bhi ph7:T3.AH0
// vmcnt ledger (2 instr/stage, queue-verified): end-ph3 VMW(6) -> prev
// ph5,6,7 + this ph0 landed (guards ph4/ph6 reads); end-ph7 VMW(6) -> this
// ph1,2,3,4 landed (guards next ph0/ph2 reads).
// Last iter (stages skipped): end-ph3 VMW(2), end-ph5 VMW(0).
#define BMT 256
#define BNT 256
#define BKT 64

#define BARRIER() __builtin_amdgcn_s_barrier()
#define VMW(n)    asm volatile("s_waitcnt vmcnt(" #n ")" ::: "memory")

template <int MODE, typename OutT>   // MODE 0: +bias[col] -> OutT; MODE 1: +resid[row,col]
__global__ __launch_bounds__(512, 2)
void gemm256(const bf16* __restrict__ A, const bf16* __restrict__ B,
             const float* __restrict__ aux, OutT* __restrict__ C,
             int M, int N, int K) {
  __shared__ __align__(16) bf16 sA[2][BMT][BKT];   // 64 KiB
  __shared__ __align__(16) bf16 sB[2][BNT][BKT];   // 64 KiB

  const int tid  = threadIdx.x;
  const int wave = tid >> 6;     // 0..7
  const int lane = tid & 63;
  const int wm   = wave >> 2;    // 0..1
  const int wn   = wave & 3;     // 0..3
  const int fr   = lane & 15;
  const int ks   = lane >> 4;
  const int sx   = fr & 7;       // read-side slot XOR = row & 7

  // bijective XCD swizzle, bn-fast within an XCD (A panel hot in XCD L2)
  const int nwg = gridDim.x;           // 448, % 8 == 0
  const int cpx = nwg >> 3;
  const int swz = (blockIdx.x & 7) * cpx + (blockIdx.x >> 3);
  const int gn  = N / BNT;
  const int bm  = (swz / gn) * BMT;
  const int bn  = (swz % gn) * BNT;

  const bf16* Ab = A + (size_t)bm * K;
  const bf16* Bb = B + (size_t)bn * K;

  const int NT = K / BKT;   // 56 (even)

  // staging: one 64-row chunk (8KB): wave w rows [rbase+w*8,+8);
  // lane: row = l>>3, slot = l&7; source pre-swizzled slot = (l&7)^(row&7)
  const int srw = lane >> 3;    // 0..7  (== row&7)
  const int ssl = lane & 7;

  auto stage64 = [&](const bf16* gpanel, int kt, bf16* ldst, int rbase) {
    const int r  = rbase + wave * 8 + srw;            // tile-local row
    const int sg = ssl ^ srw;                         // pre-swizzled source slot
    const bf16* src = gpanel + (size_t)r * K + (size_t)kt * BKT + sg * 8;
    __builtin_amdgcn_global_load_lds(
        (const __attribute__((address_space(1))) void*)src,
        (__attribute__((address_space(3))) void*)(ldst + (size_t)(wave * 8) * BKT),
        16, 0, 0);
  };
  // kinds: 0=A_H0{0,128}, 1=A_H1{64,192}, 2=B_lo{0,64}, 3=B_hi{128,192}
  auto stage16k = [&](int kind, int buf, int kt) {
    if (kt >= NT) return;
    if (kind == 0)      { stage64(Ab, kt, &sA[buf][0][0],   0);   stage64(Ab, kt, &sA[buf][128][0], 128); }
    else if (kind == 1) { stage64(Ab, kt, &sA[buf][64][0],  64);  stage64(Ab, kt, &sA[buf][192][0], 192); }
    else if (kind == 2) { stage64(Bb, kt, &sB[buf][0][0],   0);   stage64(Bb, kt, &sB[buf][64][0],  64); }
    else                { stage64(Bb, kt, &sB[buf][128][0], 128); stage64(Bb, kt, &sB[buf][192][0], 192); }
  };

  f32x4 acc[8][4];
#pragma unroll
  for (int i = 0; i < 8; ++i)
#pragma unroll
    for (int j = 0; j < 4; ++j)
      acc[i][j] = (f32x4){0.f, 0.f, 0.f, 0.f};

  bf16x8 bfr[4][2];       // B frags, whole tile (loaded at q0, live q0-q3)
  bf16x8 afr[2][2];       // A frags for the current phase

  auto loadA = [&](int buf, int qq) {
#pragma unroll
    for (int i = 0; i < 2; ++i)
#pragma unroll
      for (int kk = 0; kk < 2; ++kk) {
        const int R  = wm * 128 + qq * 32 + i * 16 + fr;
        const int sp = (kk * 4 + ks) ^ sx;
        afr[i][kk] = *(const bf16x8*)&sA[buf][R][sp * 8];
      }
  };
  auto loadB = [&](int buf) {
#pragma unroll
    for (int j = 0; j < 4; ++j)
#pragma unroll
      for (int kk = 0; kk < 2; ++kk) {
        const int R  = wn * 64 + j * 16 + fr;
        const int sp = (kk * 4 + ks) ^ sx;
        bfr[j][kk] = *(const bf16x8*)&sB[buf][R][sp * 8];
      }
  };
  auto domfma = [&](int q) {
#pragma unroll
    for (int i = 0; i < 2; ++i)
#pragma unroll
      for (int j = 0; j < 4; ++j)
#pragma unroll
        for (int kk = 0; kk < 2; ++kk)
          acc[q * 2 + i][j] = __builtin_amdgcn_mfma_f32_16x16x32_bf16(
              afr[i][kk], bfr[j][kk], acc[q * 2 + i][j], 0, 0, 0);
  };

  // prologue: tile0 complete (8 instr/wave), tile1 B + A_H0 (6 instr/wave)
  stage16k(2, 0, 0); stage16k(3, 0, 0); stage16k(0, 0, 0); stage16k(1, 0, 0);
  stage16k(2, 1, 1); stage16k(3, 1, 1); stage16k(0, 1, 1);
  VMW(6);   // tile0 fully landed
  BARRIER();

  const int nit = NT / 2;   // 28

  for (int it = 0; it < nit; ++it) {
    const bool last = (it == nit - 1);
#pragma unroll
    for (int u = 0; u < 2; ++u) {          // tile kt = 2*it+u, buf u
#pragma unroll
      for (int q = 0; q < 4; ++q) {        // phase within tile
        const int ph = u * 4 + q;
        // ---- ds_read this phase's fragments (compiler-managed waits) ----
        loadA(u, q);
        if (q == 0) loadB(u);
        // ---- staggered 16KB stage (targets proven-dead regions) ----
        if (ph == 0)      stage16k(1, 1, 2 * it + 1);   // A_H1 of tile 2it+1
        else if (ph == 1) stage16k(2, 0, 2 * it + 2);   // B_lo  tile 2it+2
        else if (ph == 2) stage16k(3, 0, 2 * it + 2);   // B_hi
        else if (ph == 3) stage16k(0, 0, 2 * it + 2);   // A_H0
        else if (ph == 4) stage16k(1, 0, 2 * it + 2);   // A_H1
        else if (ph == 5) stage16k(2, 1, 2 * it + 3);   // B_lo  tile 2it+3
        else if (ph == 6) stage16k(3, 1, 2 * it + 3);   // B_hi
        else              stage16k(0, 1, 2 * it + 3);   // A_H0
        BARRIER();
        __builtin_amdgcn_s_setprio(1);
        domfma(q);
        __builtin_amdgcn_s_setprio(0);
        // ---- counted vmcnt waits (ledger in header comment) ----
        if (ph == 3) {
          if (!last) { VMW(6); } else { VMW(2); }
        } else if (ph == 5) {
          if (last)  { VMW(0); }
        } else if (ph == 7) {
          if (!last) { VMW(6); }
        }
        BARRIER();
      }
    }
  }

  // epilogue: C/D layout col = lane&15, row = 4*(lane>>4) + reg
#pragma unroll
  for (int f = 0; f < 8; ++f) {
    const int rb = bm + wm * 128 + f * 16 + ks * 4;
#pragma unroll
    for (int j = 0; j < 4; ++j) {
      const int col = bn + wn * 64 + j * 16 + fr;
#pragma unroll
      for (int r = 0; r < 4; ++r) {
        const int row = rb + r;
        float v = acc[f][j][r];
        if (MODE == 0) v += aux[col];
        else           v += aux[(size_t)row * N + col];
        stv(&C[(size_t)row * N + col], v);
      }
    }
  }
}

// ---------------- launch ----------------
extern "C" void kernel_launch(void* const* d_in, const int* in_sizes, int n_in,
                              void* d_out, int out_size, void* d_ws, size_t ws_size,
                              hipStream_t stream) {
  (void)in_sizes; (void)n_in; (void)out_size; (void)ws_size;
  const float* x    = (const float*)d_in[0];
  const int*   pos  = (const int*)d_in[1];
  const float* ln_w = (const float*)d_in[2];
  const float* Wq   = (const float*)d_in[3];
  const float* bq   = (const float*)d_in[4];
  const float* Wo   = (const float*)d_in[9];
  float* out = (float*)d_out;

  char* ws = (char*)d_ws;
  size_t off = 0;
  bf16* h    = (bf16*)(ws + off); off += (size_t)NTOK * HIDDEN * sizeof(bf16);
  bf16* q    = (bf16*)(ws + off); off += (size_t)NTOK * NQ * sizeof(bf16);
  bf16* Wqb  = (bf16*)(ws + off); off += (size_t)NQ * HIDDEN * sizeof(bf16);
  bf16* Wob  = (bf16*)(ws + off); off += (size_t)HIDDEN * NQ * sizeof(bf16);
  float2* tab = (float2*)(ws + off); off += (size_t)NTOK * NPAIR * sizeof(float2);

  const int n4 = NQ * HIDDEN / 4;
  cvt_f32_bf16<<<(n4 + 255) / 256, 256, 0, stream>>>(Wq, Wqb, n4);
  cvt_f32_bf16<<<(n4 + 255) / 256, 256, 0, stream>>>(Wo, Wob, n4);
  rmsnorm_k<<<NTOK, 256, 0, stream>>>(x, ln_w, h);
  rope_tab_k<<<(NTOK * NPAIR) / 256, 256, 0, stream>>>(pos, tab);

  const int nblk = (NTOK / BMT) * (NQ / BNT);   // 32 * 14 = 448 (%8 == 0)
  gemm256<0, bf16><<<nblk, 512, 0, stream>>>(h, Wqb, bq, q, NTOK, NQ, HIDDEN);
  rope_apply_k<<<NTOK, 256, 0, stream>>>(q, tab);
  gemm256<1, float><<<nblk, 512, 0, stream>>>(q, Wob, x, out, NTOK, HIDDEN, NQ);
}